// Round 5
// baseline (963.109 us; speedup 1.0000x reference)
//
#include <hip/hip_runtime.h>

// Bag-level attention selector — TWO-PASS restructure.
//
//   repre:        (200000, 690) fp32   <- 552 MB, dominant HBM traffic
//   relation_mat: (53, 690) fp32
//   bias:         (53,) fp32
//   scope:        (25000, 2) int       (contiguous [start,end) per bag)
//   labels:       (200000,) int
//   out:          (25000, 53) fp32
//   workspace:    logits (200000 fp32 = 800 KB)
//
// Round-4 post-mortem: wave-per-bag fused kernel stuck at ~372 us/dispatch
// with ALL pipes <20% busy; three rounds of ILP surgery moved it 465->~340
// ->372 while latency models kept predicting ~30-70 us. Isolate the mystery:
//
// Pass 1 (logit_kernel): rel_logits[n] = dot(repre[n], rel[labels[n]]).
//   One wave per row, 200000 independent waves, pure 552 MB stream.
//   TLP-saturated by construction -> must run near achievable BW.
//
// Pass 2 (bag_attn_kernel): per-bag softmax computed UP FRONT from logits
//   (one coalesced lane-load per 64-row window + two shfl reductions), then
//   the bag loop is pure weighted accumulation: independent clamped repre
//   loads, weights broadcast from registers, no gathers, no reductions,
//   no exp, no rescale in the loop. Phase C (rel x att, verified) unchanged.

#define NROWS  200000
#define NBAGS  25000
#define DDIM   690
#define D2     345      // float2 elements per row (rows are 8B-aligned)
#define RREL   53
#define NEG_INF (-3.402823466e38f)

static __device__ __forceinline__ int imin(int a, int b) { return a < b ? a : b; }

// ---------------------------------------------------------------- pass 1
#define L_WAVES 8
#define L_BLOCK 512

__global__ __launch_bounds__(L_BLOCK, 4) void logit_kernel(
    const float* __restrict__ repre,
    const float* __restrict__ rel,
    const int*   __restrict__ labels,
    float*       __restrict__ logits)
{
    const int lane = threadIdx.x & 63;
    const int wave = threadIdx.x >> 6;
    const int row  = blockIdx.x * L_WAVES + wave;   // grid exact: 200000 rows

    const int lab = labels[row];                    // wave-uniform scalar load
    const float2* rp = (const float2*)(repre + (size_t)row * DDIM);
    const float2* rl = (const float2*)rel + (size_t)lab * D2;

    float d = 0.f;
    #pragma unroll
    for (int k = 0; k < 6; ++k) {
        const int f = lane + 64 * k;
        if (f < D2) {
            const float2 a = rp[f];
            const float2 b = rl[f];
            d = fmaf(a.x, b.x, fmaf(a.y, b.y, d));
        }
    }
    #pragma unroll
    for (int o = 32; o; o >>= 1) d += __shfl_xor(d, o, 64);
    if (lane == 0) logits[row] = d;
}

// ---------------------------------------------------------------- pass 2
#define WAVES  4
#define BLOCK  256      // 4 waves
#define CHUNK  8
#define WIN    64

__global__ __launch_bounds__(BLOCK, 2) void bag_attn_kernel(
    const float* __restrict__ repre,
    const float* __restrict__ rel,
    const float* __restrict__ bias,
    const int*   __restrict__ scope,
    const float* __restrict__ logits,
    float*       __restrict__ out)
{
    __shared__ float s_att[WAVES * DDIM];   // 11 KB: 4 normalized att vectors

    const int tid  = threadIdx.x;
    const int lane = tid & 63;
    const int wave = tid >> 6;
    const int bag  = blockIdx.x * WAVES + wave;

    const int start = scope[2 * bag];
    const int end   = scope[2 * bag + 1];   // every bag has >= 1 row

    // ---- per-bag softmax stats from logits (lane-parallel, windowed) ----
    float m = NEG_INF;
    float l = 0.f;
    for (int w0 = start; w0 < end; w0 += WIN) {
        const int idx = w0 + lane;
        float lg = logits[imin(idx, end - 1)];
        if (idx >= end) lg = NEG_INF;        // mask: exp -> 0
        float wm = lg;
        #pragma unroll
        for (int o = 32; o; o >>= 1) wm = fmaxf(wm, __shfl_xor(wm, o, 64));
        const float nm = fmaxf(m, wm);       // finite: >= 1 real row
        const float e  = __expf(lg - nm);    // masked lanes: 0
        float s = e;
        #pragma unroll
        for (int o = 32; o; o >>= 1) s += __shfl_xor(s, o, 64);
        l = fmaf(l, __expf(m - nm), s);
        m = nm;
    }
    const float inv = 1.f / l;

    // ---- weighted accumulation: pure streaming, weights pre-known ----
    float2 acc[6];
    #pragma unroll
    for (int k = 0; k < 6; ++k) acc[k] = make_float2(0.f, 0.f);

    for (int w0 = start; w0 < end; w0 += WIN) {
        const int idx = w0 + lane;
        const float lg = logits[imin(idx, end - 1)];
        // final weight of row (w0+lane); 0 for masked lanes
        const float ev = (idx < end) ? __expf(lg - m) * inv : 0.f;
        const int wend = imin(w0 + WIN, end);

        for (int row = w0; row < wend; row += CHUNK) {
            // 48 unconditional clamped coalesced loads, all independent.
            float2 v[CHUNK][6];
            #pragma unroll
            for (int i = 0; i < CHUNK; ++i) {
                const int rc = imin(row + i, end - 1);
                const float2* rp = (const float2*)(repre + (size_t)rc * DDIM);
                #pragma unroll
                for (int k = 0; k < 6; ++k) {
                    const int f = lane + 64 * k;
                    v[i][k] = (f < D2) ? rp[f] : make_float2(0.f, 0.f);
                }
            }
            // Broadcast weights from registers. Index row-w0+i <= 63 by
            // construction; rows past end land on a lane whose ev == 0,
            // so clamped duplicate rows contribute exactly zero.
            float w[CHUNK];
            #pragma unroll
            for (int i = 0; i < CHUNK; ++i)
                w[i] = __shfl(ev, row - w0 + i, 64);

            #pragma unroll
            for (int k = 0; k < 6; ++k) {
                float ax = acc[k].x, ay = acc[k].y;
                #pragma unroll
                for (int i = 0; i < CHUNK; ++i) {
                    ax = fmaf(w[i], v[i][k].x, ax);
                    ay = fmaf(w[i], v[i][k].y, ay);
                }
                acc[k].x = ax; acc[k].y = ay;
            }
        }
    }

    // Publish att vector to LDS (already normalized: weights summed to 1).
    float2* satt2 = (float2*)(s_att + wave * DDIM);
    #pragma unroll
    for (int k = 0; k < 6; ++k) {
        const int f = lane + 64 * k;
        if (f < D2) satt2[f] = acc[k];
    }
    __syncthreads();

    // Phase C: out[bag0+g, r] = dot(att[g], rel[r]) + bias[r]
    const float2* rel2 = (const float2*)rel;
    const int bag0 = blockIdx.x * WAVES;
    for (int r = wave; r < RREL; r += WAVES) {
        const float2* rl = rel2 + (size_t)r * D2;
        float2 u[6];
        #pragma unroll
        for (int k = 0; k < 6; ++k) {
            const int f = lane + 64 * k;
            u[k] = (f < D2) ? rl[f] : make_float2(0.f, 0.f);
        }
        const float b = bias[r];
        #pragma unroll
        for (int g = 0; g < WAVES; ++g) {
            const float2* a2 = (const float2*)(s_att + g * DDIM);
            float dot = 0.f;
            #pragma unroll
            for (int k = 0; k < 6; ++k) {
                const int f = lane + 64 * k;
                if (f < D2) {
                    const float2 a = a2[f];
                    dot = fmaf(u[k].x, a.x, fmaf(u[k].y, a.y, dot));
                }
            }
            #pragma unroll
            for (int o = 32; o; o >>= 1) dot += __shfl_xor(dot, o, 64);
            if (lane == 0) out[(size_t)(bag0 + g) * RREL + r] = dot + b;
        }
    }
}

extern "C" void kernel_launch(void* const* d_in, const int* in_sizes, int n_in,
                              void* d_out, int out_size, void* d_ws, size_t ws_size,
                              hipStream_t stream)
{
    const float* repre  = (const float*)d_in[0];
    const float* rel    = (const float*)d_in[1];
    const float* bias   = (const float*)d_in[2];
    const int*   scope  = (const int*)d_in[3];
    const int*   labels = (const int*)d_in[4];
    float*       out    = (float*)d_out;
    float*       logits = (float*)d_ws;     // 800 KB of workspace

    const int lgrid = NROWS / L_WAVES;      // 25000, exact
    logit_kernel<<<lgrid, L_BLOCK, 0, stream>>>(repre, rel, labels, logits);

    const int grid = NBAGS / WAVES;         // 6250, exact
    bag_attn_kernel<<<grid, BLOCK, 0, stream>>>(repre, rel, bias, scope, logits, out);
}